// Round 6
// baseline (244.058 us; speedup 1.0000x reference)
//
#include <hip/hip_runtime.h>
#include <hip/hip_bf16.h>

#define B_ 2
#define T_ 4096
#define D_ 2048
#define H_ 4
#define NC 176            // combined proj cols: 128 q | 32 k | 4 w | 12 pad
#define ROWS (B_ * T_)    // 8192
#define NT 11             // n-tiles of 16 rows
#define TILE_E (16 * NC)  // 2816 elems per 16-row tile of Cb2
#define WTILE_E (16 * D_) // 32768 elems per 16-row n-tile of Wcb2

typedef __attribute__((ext_vector_type(8))) short short8;   // 8 x bf16
typedef __attribute__((ext_vector_type(4))) short short4v;  // 4 x bf16
typedef __attribute__((ext_vector_type(4))) float f32x4;
typedef __attribute__((ext_vector_type(4))) float float4v;

__device__ inline unsigned short f2bf(float f) {
  unsigned u = __float_as_uint(f);
  u += 0x7fffu + ((u >> 16) & 1u);   // RNE
  return (unsigned short)(u >> 16);
}
__device__ inline float bf2f(unsigned short s) {
  return __uint_as_float(((unsigned)s) << 16);
}

// ---------------- Kernel 1: pack weights into octet-tiled bf16 --------------
// Wcb2 layout: E(n, r, k) = n*32768 + (k>>3)*128 + r*8 + (k&7)
__global__ __launch_bounds__(256) void pack_weights(const float* __restrict__ Wq,
                                                    const float* __restrict__ Ww,
                                                    const float* __restrict__ Wk,
                                                    unsigned short* __restrict__ Wcb) {
  int idx = blockIdx.x * 256 + threadIdx.x;
  if (idx >= NC * D_) return;
  int row = idx / D_, col = idx - row * D_;
  float v = 0.f;
  if (row < 128)       v = Wq[row * D_ + col];
  else if (row < 160)  v = Wk[(row - 128) * D_ + col];
  else if (row < 164)  v = Ww[(row - 160) * D_ + col];
  int n = row >> 4, r = row & 15;
  size_t dst = (size_t)n * WTILE_E + (size_t)(col >> 3) * 128 + r * 8 + (col & 7);
  Wcb[dst] = f2bf(v);
}

// ---------------- Kernel 2: Cb2 = bf16(hs) @ Wcb^T (tiled layouts) ----------
// DIAGNOSTIC: runtime `reps` loop (idempotent) to lift this dispatch above
// the 74us fillBuffer floor so its counters show in top-5. Body == R5.
__global__ __launch_bounds__(256) void proj_kernel(const float* __restrict__ hs,
                                                   const unsigned short* __restrict__ Wcb,
                                                   unsigned short* __restrict__ Cb,
                                                   int reps) {
  __shared__ f32x4 red[3][11][64];   // 33,792 B

  int wid  = threadIdx.x >> 6;
  int lane = threadIdx.x & 63;
  int lr = lane & 15, lo = lane >> 4;
  int row0 = blockIdx.x * 16;
  int k0   = wid * 512;

  for (int rep = 0; rep < reps; ++rep) {
    int zoff = 0;
    asm volatile("" : "+v"(zoff));   // opaque 0: block cross-rep CSE

    const float*          ap    = hs  + (size_t)(row0 + lr) * D_ + k0 + lo * 8 + zoff;
    const unsigned short* bbase = Wcb + (size_t)k0 * 16 + lo * 128 + lr * 8 + zoff;

    f32x4 acc[11];
#pragma unroll
    for (int n = 0; n < 11; ++n) acc[n] = (f32x4){0.f, 0.f, 0.f, 0.f};

    float4v A0[2], A1[2];
    short8  Bv[2][11];

    A0[0] = *(const float4v*)(ap);
    A1[0] = *(const float4v*)(ap + 4);
#pragma unroll
    for (int n = 0; n < 11; ++n)
      Bv[0][n] = *(const short8*)(bbase + (size_t)n * WTILE_E);

#pragma unroll
    for (int s = 0; s < 16; ++s) {
      const int cur = s & 1, nxt = cur ^ 1;
      if (s < 15) {
        A0[nxt] = *(const float4v*)(ap + (s + 1) * 32);
        A1[nxt] = *(const float4v*)(ap + (s + 1) * 32 + 4);
#pragma unroll
        for (int n = 0; n < 11; ++n)
          Bv[nxt][n] = *(const short8*)(bbase + (size_t)n * WTILE_E + (s + 1) * 512);
      }
      short8 a;
#pragma unroll
      for (int i = 0; i < 4; ++i) {
        a[i]     = (short)f2bf(A0[cur][i]);
        a[i + 4] = (short)f2bf(A1[cur][i]);
      }
#pragma unroll
      for (int n = 0; n < 11; ++n)
        acc[n] = __builtin_amdgcn_mfma_f32_16x16x32_bf16(a, Bv[cur][n], acc[n], 0, 0, 0);
    }

    if (wid != 0) {
#pragma unroll
      for (int n = 0; n < 11; ++n) red[wid - 1][n][lane] = acc[n];
    }
    __syncthreads();

    if (wid == 0) {
#pragma unroll
      for (int n = 0; n < 11; ++n) {
        f32x4 r0 = red[0][n][lane], r1 = red[1][n][lane], r2 = red[2][n][lane];
#pragma unroll
        for (int r = 0; r < 4; ++r) acc[n][r] += r0[r] + r1[r] + r2[r];
      }
      unsigned short* cb = Cb + (size_t)(row0 >> 4) * TILE_E + (lr & 7);
#pragma unroll
      for (int n = 0; n < 11; ++n) {
        int oct = n * 2 + (lr >> 3);
#pragma unroll
        for (int r = 0; r < 4; ++r)
          cb[oct * 128 + (lo * 4 + r) * 8] = f2bf(acc[n][r]);
      }
    }
    __syncthreads();   // red reused next rep
  }
}

// ---------------- Kernel 3: out[b,t,s] = sum_h w[t,h]*relu(q[t,h,:].k[s,:]) -
// DIAGNOSTIC: runtime `reps` loop, body == R5.
__global__ __launch_bounds__(256) void score_kernel(const unsigned short* __restrict__ Cb,
                                                    float* __restrict__ out,
                                                    int reps) {
  int b = blockIdx.z, tb = blockIdx.y, sb = blockIdx.x;
  int wid  = threadIdx.x >> 6;
  int lane = threadIdx.x & 63;
  int lr = lane & 15, lo = lane >> 4;
  int wm = wid >> 1, wn = wid & 1;
  int t_base = tb * 128 + wm * 64;
  int s_base = sb * 128 + wn * 64;

  for (int rep = 0; rep < reps; ++rep) {
    int zoff = 0;
    asm volatile("" : "+v"(zoff));   // opaque 0: block cross-rep CSE

    const unsigned short* C2 = Cb + (size_t)b * (T_ / 16) * TILE_E + zoff;
    float* O = out + (size_t)b * T_ * T_ + zoff;

    short8 bf[4];
#pragma unroll
    for (int n = 0; n < 4; ++n)
      bf[n] = *(const short8*)(C2 + (size_t)((s_base >> 4) + n) * TILE_E +
                               (16 + lo) * 128 + lr * 8);

    const f32x4 zero = (f32x4){0.f, 0.f, 0.f, 0.f};

#pragma unroll
    for (int m = 0; m < 4; ++m) {
      const unsigned short* Ct = C2 + (size_t)((t_base >> 4) + m) * TILE_E;

      short8 af[H_];
#pragma unroll
      for (int h = 0; h < H_; ++h)
        af[h] = *(const short8*)(Ct + (h * 4 + lo) * 128 + lr * 8);

      float wv[4][H_];
      const unsigned short* wp = Ct + 20 * 128 + lo * 32;
#pragma unroll
      for (int r = 0; r < 4; ++r) {
        short4v w4 = *(const short4v*)(wp + r * 8);
#pragma unroll
        for (int h = 0; h < H_; ++h) wv[r][h] = bf2f((unsigned short)w4[h]);
      }

      int tc = t_base + m * 16 + lo * 4;
#pragma unroll
      for (int n = 0; n < 4; ++n) {
        f32x4 o = zero;
#pragma unroll
        for (int h = 0; h < H_; ++h) {
          f32x4 c = __builtin_amdgcn_mfma_f32_16x16x32_bf16(af[h], bf[n], zero, 0, 0, 0);
#pragma unroll
          for (int r = 0; r < 4; ++r) o[r] += wv[r][h] * fmaxf(c[r], 0.f);
        }
        int sc = s_base + n * 16 + lr;
#pragma unroll
        for (int r = 0; r < 4; ++r)
          O[(size_t)(tc + r) * T_ + sc] = o[r];
      }
    }
  }
}

// ---------------------------------------------------------------------------
extern "C" void kernel_launch(void* const* d_in, const int* in_sizes, int n_in,
                              void* d_out, int out_size, void* d_ws, size_t ws_size,
                              hipStream_t stream) {
  const float* hs = (const float*)d_in[0];
  const float* Wq = (const float*)d_in[1];
  const float* Ww = (const float*)d_in[2];
  const float* Wk = (const float*)d_in[3];
  float* out = (float*)d_out;

  unsigned short* Wcb = (unsigned short*)d_ws;                      // 720,896 B
  unsigned short* Cb  = (unsigned short*)((char*)d_ws + (1 << 20)); // 2,883,584 B

  pack_weights<<<(NC * D_ + 255) / 256, 256, 0, stream>>>(Wq, Ww, Wk, Wcb);
  proj_kernel<<<ROWS / 16, 256, 0, stream>>>(hs, Wcb, Cb, 6);
  dim3 g(T_ / 128, T_ / 128, B_);
  score_kernel<<<g, 256, 0, stream>>>(Cb, out, 4);
}

// Round 7
// 65.253 us; speedup vs baseline: 3.7402x; 3.7402x over previous
//
#include <hip/hip_runtime.h>
#include <hip/hip_bf16.h>

#define B_ 2
#define T_ 4096
#define D_ 2048
#define H_ 4
#define NC 176            // combined proj cols: 128 q | 32 k | 4 w | 12 pad
#define ROWS (B_ * T_)    // 8192
#define TILE_E (16 * NC)  // 2816 elems per 16-row tile of Cb2
#define WTILE_E (16 * D_) // 32768 elems per 16-row n-tile of Wcb2

typedef __attribute__((ext_vector_type(8))) short short8;   // 8 x bf16
typedef __attribute__((ext_vector_type(4))) short short4v;  // 4 x bf16
typedef __attribute__((ext_vector_type(4))) float f32x4;
typedef __attribute__((ext_vector_type(4))) float float4v;

__device__ inline unsigned short f2bf(float f) {
  unsigned u = __float_as_uint(f);
  u += 0x7fffu + ((u >> 16) & 1u);   // RNE
  return (unsigned short)(u >> 16);
}
__device__ inline float bf2f(unsigned short s) {
  return __uint_as_float(((unsigned)s) << 16);
}

// ---------------- Kernel 1: pack weights into octet-tiled bf16 --------------
// Wcb2 layout: E(n, r, k) = n*32768 + (k>>3)*128 + r*8 + (k&7)
__global__ __launch_bounds__(256) void pack_weights(const float* __restrict__ Wq,
                                                    const float* __restrict__ Ww,
                                                    const float* __restrict__ Wk,
                                                    unsigned short* __restrict__ Wcb) {
  int idx = blockIdx.x * 256 + threadIdx.x;
  if (idx >= NC * D_) return;
  int row = idx / D_, col = idx - row * D_;
  float v = 0.f;
  if (row < 128)       v = Wq[row * D_ + col];
  else if (row < 160)  v = Wk[(row - 128) * D_ + col];
  else if (row < 164)  v = Ww[(row - 160) * D_ + col];
  int n = row >> 4, r = row & 15;
  size_t dst = (size_t)n * WTILE_E + (size_t)(col >> 3) * 128 + r * 8 + (col & 7);
  Wcb[dst] = f2bf(v);
}

// ---------------- Kernel 2: Cb2 = bf16(hs) @ Wcb^T (tiled layouts) ----------
// M_rep=2: each wave computes TWO 16-row m-tiles with the SAME B-fragments
// (halves B L2 traffic to 180 MB, doubles per-wave ILP). Split-K=4 across
// waves, block covers 32 rows, grid = 256 blocks. Register double-buffer,
// fully unrolled 16-step loop. 4-way LDS reduce; waves 0/1 finalize m=0/1.
__global__ __launch_bounds__(256) void proj_kernel(const float* __restrict__ hs,
                                                   const unsigned short* __restrict__ Wcb,
                                                   unsigned short* __restrict__ Cb) {
  __shared__ f32x4 red[4][2][11][64];   // 90,112 B -> 1 block/CU

  int wid  = threadIdx.x >> 6;
  int lane = threadIdx.x & 63;
  int lr = lane & 15, lo = lane >> 4;
  int row0 = blockIdx.x * 32;
  int k0   = wid * 512;

  const float* ap0 = hs + (size_t)(row0 + lr) * D_ + k0 + lo * 8;
  const float* ap1 = ap0 + (size_t)16 * D_;
  const unsigned short* bbase = Wcb + (size_t)k0 * 16 + lo * 128 + lr * 8;

  f32x4 acc[2][11];
#pragma unroll
  for (int m = 0; m < 2; ++m)
#pragma unroll
    for (int n = 0; n < 11; ++n) acc[m][n] = (f32x4){0.f, 0.f, 0.f, 0.f};

  float4v A[2][2][2];   // [m][buf][half]
  short8  Bv[2][11];

  // prologue: load step 0
  A[0][0][0] = *(const float4v*)(ap0);
  A[0][0][1] = *(const float4v*)(ap0 + 4);
  A[1][0][0] = *(const float4v*)(ap1);
  A[1][0][1] = *(const float4v*)(ap1 + 4);
#pragma unroll
  for (int n = 0; n < 11; ++n)
    Bv[0][n] = *(const short8*)(bbase + (size_t)n * WTILE_E);

#pragma unroll
  for (int s = 0; s < 16; ++s) {
    const int cur = s & 1, nxt = cur ^ 1;
    if (s < 15) {   // issue next-step loads BEFORE this step's MFMAs
      A[0][nxt][0] = *(const float4v*)(ap0 + (s + 1) * 32);
      A[0][nxt][1] = *(const float4v*)(ap0 + (s + 1) * 32 + 4);
      A[1][nxt][0] = *(const float4v*)(ap1 + (s + 1) * 32);
      A[1][nxt][1] = *(const float4v*)(ap1 + (s + 1) * 32 + 4);
#pragma unroll
      for (int n = 0; n < 11; ++n)
        Bv[nxt][n] = *(const short8*)(bbase + (size_t)n * WTILE_E + (s + 1) * 512);
    }
    short8 a0, a1;
#pragma unroll
    for (int i = 0; i < 4; ++i) {
      a0[i]     = (short)f2bf(A[0][cur][0][i]);
      a0[i + 4] = (short)f2bf(A[0][cur][1][i]);
      a1[i]     = (short)f2bf(A[1][cur][0][i]);
      a1[i + 4] = (short)f2bf(A[1][cur][1][i]);
    }
#pragma unroll
    for (int n = 0; n < 11; ++n) {
      acc[0][n] = __builtin_amdgcn_mfma_f32_16x16x32_bf16(a0, Bv[cur][n], acc[0][n], 0, 0, 0);
      acc[1][n] = __builtin_amdgcn_mfma_f32_16x16x32_bf16(a1, Bv[cur][n], acc[1][n], 0, 0, 0);
    }
  }

#pragma unroll
  for (int m = 0; m < 2; ++m)
#pragma unroll
    for (int n = 0; n < 11; ++n) red[wid][m][n][lane] = acc[m][n];
  __syncthreads();

  if (wid < 2) {
    const int m = wid;
    // Cb2 layout: F(t,c) = (t>>4)*TILE_E + (c>>3)*128 + (t&15)*8 + (c&7)
    unsigned short* cb = Cb + (size_t)((row0 >> 4) + m) * TILE_E + (lr & 7);
#pragma unroll
    for (int n = 0; n < 11; ++n) {
      f32x4 t = red[0][m][n][lane];
#pragma unroll
      for (int w = 1; w < 4; ++w) {
        f32x4 p = red[w][m][n][lane];
#pragma unroll
        for (int r = 0; r < 4; ++r) t[r] += p[r];
      }
      int oct = n * 2 + (lr >> 3);
#pragma unroll
      for (int r = 0; r < 4; ++r)
        cb[oct * 128 + (lo * 4 + r) * 8] = f2bf(t[r]);
    }
  }
}

// ---------------- Kernel 3: out[b,t,s] = sum_h w[t,h]*relu(q[t,h,:].k[s,:]) -
// grid (S/128, T/128, B), block 256 (4 waves, 2x2 quadrants of 64x64).
// Epilogue: per-wave LDS transpose so each global store is a 256-B-contiguous
// per-row run (global_store_dwordx4), matching fillBuffer's write pattern.
__global__ __launch_bounds__(256) void score_kernel(const unsigned short* __restrict__ Cb,
                                                    float* __restrict__ out) {
  __shared__ __align__(16) float tbuf[4][16][72];   // 18,432 B, wave-private

  int b = blockIdx.z, tb = blockIdx.y, sb = blockIdx.x;
  int wid  = threadIdx.x >> 6;
  int lane = threadIdx.x & 63;
  int lr = lane & 15, lo = lane >> 4;
  int wm = wid >> 1, wn = wid & 1;
  int t_base = tb * 128 + wm * 64;
  int s_base = sb * 128 + wn * 64;

  const unsigned short* C2 = Cb + (size_t)b * (T_ / 16) * TILE_E;
  float* O = out + (size_t)b * T_ * T_;

  // B-frags (k part, cols 128..159 -> octet 16+lo): shared across heads
  short8 bf[4];
#pragma unroll
  for (int n = 0; n < 4; ++n)
    bf[n] = *(const short8*)(C2 + (size_t)((s_base >> 4) + n) * TILE_E +
                             (16 + lo) * 128 + lr * 8);

  const f32x4 zero = (f32x4){0.f, 0.f, 0.f, 0.f};
  int rr = lane >> 4;          // epilogue read: row-in-group 0..3
  int cq = (lane & 15) * 4;    // epilogue read: col 0..60 step 4

#pragma unroll
  for (int m = 0; m < 4; ++m) {
    const unsigned short* Ct = C2 + (size_t)((t_base >> 4) + m) * TILE_E;

    short8 af[H_];
#pragma unroll
    for (int h = 0; h < H_; ++h)
      af[h] = *(const short8*)(Ct + (h * 4 + lo) * 128 + lr * 8);

    float wv[4][H_];
    const unsigned short* wp = Ct + 20 * 128 + lo * 32;
#pragma unroll
    for (int r = 0; r < 4; ++r) {
      short4v w4 = *(const short4v*)(wp + r * 8);
#pragma unroll
      for (int h = 0; h < H_; ++h) wv[r][h] = bf2f((unsigned short)w4[h]);
    }

    f32x4 o4[4];
#pragma unroll
    for (int n = 0; n < 4; ++n) {
      f32x4 o = zero;
#pragma unroll
      for (int h = 0; h < H_; ++h) {
        f32x4 c = __builtin_amdgcn_mfma_f32_16x16x32_bf16(af[h], bf[n], zero, 0, 0, 0);
#pragma unroll
        for (int r = 0; r < 4; ++r) o[r] += wv[r][h] * fmaxf(c[r], 0.f);
      }
      o4[n] = o;
    }

    // transpose via wave-private LDS: write C/D-layout, read row-contiguous
#pragma unroll
    for (int n = 0; n < 4; ++n)
#pragma unroll
      for (int r = 0; r < 4; ++r)
        tbuf[wid][lo * 4 + r][n * 16 + lr] = o4[n][r];

    float* Om = O + (size_t)(t_base + m * 16) * T_ + s_base;
#pragma unroll
    for (int j = 0; j < 4; ++j) {
      float4v v = *(const float4v*)&tbuf[wid][rr + 4 * j][cq];
      *(float4v*)(Om + (size_t)(rr + 4 * j) * T_ + cq) = v;
    }
  }
}

// ---------------------------------------------------------------------------
extern "C" void kernel_launch(void* const* d_in, const int* in_sizes, int n_in,
                              void* d_out, int out_size, void* d_ws, size_t ws_size,
                              hipStream_t stream) {
  const float* hs = (const float*)d_in[0];
  const float* Wq = (const float*)d_in[1];
  const float* Ww = (const float*)d_in[2];
  const float* Wk = (const float*)d_in[3];
  float* out = (float*)d_out;

  unsigned short* Wcb = (unsigned short*)d_ws;                      // 720,896 B
  unsigned short* Cb  = (unsigned short*)((char*)d_ws + (1 << 20)); // 2,883,584 B

  pack_weights<<<(NC * D_ + 255) / 256, 256, 0, stream>>>(Wq, Ww, Wk, Wcb);
  proj_kernel<<<ROWS / 32, 256, 0, stream>>>(hs, Wcb, Cb);
  dim3 g(T_ / 128, T_ / 128, B_);
  score_kernel<<<g, 256, 0, stream>>>(Cb, out);
}

// Round 8
// 62.545 us; speedup vs baseline: 3.9021x; 1.0433x over previous
//
#include <hip/hip_runtime.h>
#include <hip/hip_bf16.h>

#define B_ 2
#define T_ 4096
#define D_ 2048
#define H_ 4
#define NC 176            // combined proj cols: 128 q | 32 k | 4 w | 12 pad
#define ROWS (B_ * T_)    // 8192
#define TILE_E (16 * NC)  // 2816 elems per 16-row tile of Cb2
#define WTILE_E (16 * D_) // 32768 elems per 16-row n-tile of Wcb2

typedef __attribute__((ext_vector_type(8))) short short8;   // 8 x bf16
typedef __attribute__((ext_vector_type(4))) short short4v;  // 4 x bf16
typedef __attribute__((ext_vector_type(4))) float f32x4;
typedef __attribute__((ext_vector_type(4))) float float4v;

__device__ inline unsigned short f2bf(float f) {
  unsigned u = __float_as_uint(f);
  u += 0x7fffu + ((u >> 16) & 1u);   // RNE
  return (unsigned short)(u >> 16);
}
__device__ inline float bf2f(unsigned short s) {
  return __uint_as_float(((unsigned)s) << 16);
}

// ---------------- Kernel 1: pack weights into octet-tiled bf16 --------------
// Wcb2 layout: E(n, r, k) = n*32768 + (k>>3)*128 + r*8 + (k&7)
__global__ __launch_bounds__(256) void pack_weights(const float* __restrict__ Wq,
                                                    const float* __restrict__ Ww,
                                                    const float* __restrict__ Wk,
                                                    unsigned short* __restrict__ Wcb) {
  int idx = blockIdx.x * 256 + threadIdx.x;
  if (idx >= NC * D_) return;
  int row = idx / D_, col = idx - row * D_;
  float v = 0.f;
  if (row < 128)       v = Wq[row * D_ + col];
  else if (row < 160)  v = Wk[(row - 128) * D_ + col];
  else if (row < 164)  v = Ww[(row - 160) * D_ + col];
  int n = row >> 4, r = row & 15;
  size_t dst = (size_t)n * WTILE_E + (size_t)(col >> 3) * 128 + r * 8 + (col & 7);
  Wcb[dst] = f2bf(v);
}

// ---------------- Kernel 2: Cb2 = bf16(hs) @ Wcb^T (tiled layouts) ----------
// R5 structure (512 blocks x 4 waves, split-K=4, one 16-row m-tile/block,
// 8 waves/CU) + DEEP register prefetch: A (HBM stream) at distance 3,
// B (L2-resident) at distance 2. Fully unrolled -> all indices static.
__global__ __launch_bounds__(256) void proj_kernel(const float* __restrict__ hs,
                                                   const unsigned short* __restrict__ Wcb,
                                                   unsigned short* __restrict__ Cb) {
  __shared__ f32x4 red[3][11][64];   // 33,792 B

  int wid  = threadIdx.x >> 6;
  int lane = threadIdx.x & 63;
  int lr = lane & 15, lo = lane >> 4;
  int row0 = blockIdx.x * 16;
  int k0   = wid * 512;

  const float*          ap    = hs  + (size_t)(row0 + lr) * D_ + k0 + lo * 8;
  const unsigned short* bbase = Wcb + (size_t)k0 * 16 + lo * 128 + lr * 8;

  f32x4 acc[11];
#pragma unroll
  for (int n = 0; n < 11; ++n) acc[n] = (f32x4){0.f, 0.f, 0.f, 0.f};

  float4v A0[4], A1[4];   // A prefetch distance 3 (4 bufs, modulo-4)
  short8  Bv[3][11];      // B prefetch distance 2 (3 bufs, modulo-3)

  // prologue: A steps 0..2, B steps 0..1
#pragma unroll
  for (int p = 0; p < 3; ++p) {
    A0[p] = *(const float4v*)(ap + p * 32);
    A1[p] = *(const float4v*)(ap + p * 32 + 4);
  }
#pragma unroll
  for (int p = 0; p < 2; ++p)
#pragma unroll
    for (int n = 0; n < 11; ++n)
      Bv[p][n] = *(const short8*)(bbase + (size_t)n * WTILE_E + p * 512);

#pragma unroll
  for (int s = 0; s < 16; ++s) {
    // issue far-ahead loads BEFORE this step's compute
    if (s + 3 < 16) {
      A0[(s + 3) & 3] = *(const float4v*)(ap + (s + 3) * 32);
      A1[(s + 3) & 3] = *(const float4v*)(ap + (s + 3) * 32 + 4);
    }
    if (s + 2 < 16) {
#pragma unroll
      for (int n = 0; n < 11; ++n)
        Bv[(s + 2) % 3][n] = *(const short8*)(bbase + (size_t)n * WTILE_E + (s + 2) * 512);
    }
    short8 a;
#pragma unroll
    for (int i = 0; i < 4; ++i) {
      a[i]     = (short)f2bf(A0[s & 3][i]);
      a[i + 4] = (short)f2bf(A1[s & 3][i]);
    }
#pragma unroll
    for (int n = 0; n < 11; ++n)
      acc[n] = __builtin_amdgcn_mfma_f32_16x16x32_bf16(a, Bv[s % 3][n], acc[n], 0, 0, 0);
  }

  if (wid != 0) {
#pragma unroll
    for (int n = 0; n < 11; ++n) red[wid - 1][n][lane] = acc[n];
  }
  __syncthreads();

  if (wid == 0) {
#pragma unroll
    for (int n = 0; n < 11; ++n) {
      f32x4 r0 = red[0][n][lane], r1 = red[1][n][lane], r2 = red[2][n][lane];
#pragma unroll
      for (int r = 0; r < 4; ++r) acc[n][r] += r0[r] + r1[r] + r2[r];
    }
    // Cb2 layout: F(t,c) = (t>>4)*TILE_E + (c>>3)*128 + (t&15)*8 + (c&7)
    unsigned short* cb = Cb + (size_t)(row0 >> 4) * TILE_E + (lr & 7);
#pragma unroll
    for (int n = 0; n < 11; ++n) {
      int oct = n * 2 + (lr >> 3);
#pragma unroll
      for (int r = 0; r < 4; ++r)
        cb[oct * 128 + (lo * 4 + r) * 8] = f2bf(acc[n][r]);
    }
  }
}

// ---------------- Kernel 3: out[b,t,s] = sum_h w[t,h]*relu(q[t,h,:].k[s,:]) -
// grid (S/128, T/128, B), block 256 (4 waves, 2x2 quadrants of 64x64).
// Epilogue: per-wave LDS transpose -> 256-B-contiguous row stores (dwordx4).
__global__ __launch_bounds__(256) void score_kernel(const unsigned short* __restrict__ Cb,
                                                    float* __restrict__ out) {
  __shared__ __align__(16) float tbuf[4][16][72];   // 18,432 B, wave-private

  int b = blockIdx.z, tb = blockIdx.y, sb = blockIdx.x;
  int wid  = threadIdx.x >> 6;
  int lane = threadIdx.x & 63;
  int lr = lane & 15, lo = lane >> 4;
  int wm = wid >> 1, wn = wid & 1;
  int t_base = tb * 128 + wm * 64;
  int s_base = sb * 128 + wn * 64;

  const unsigned short* C2 = Cb + (size_t)b * (T_ / 16) * TILE_E;
  float* O = out + (size_t)b * T_ * T_;

  // B-frags (k part, cols 128..159 -> octet 16+lo): shared across heads
  short8 bf[4];
#pragma unroll
  for (int n = 0; n < 4; ++n)
    bf[n] = *(const short8*)(C2 + (size_t)((s_base >> 4) + n) * TILE_E +
                             (16 + lo) * 128 + lr * 8);

  const f32x4 zero = (f32x4){0.f, 0.f, 0.f, 0.f};
  int rr = lane >> 4;          // epilogue read: row-in-group 0..3
  int cq = (lane & 15) * 4;    // epilogue read: col 0..60 step 4

#pragma unroll
  for (int m = 0; m < 4; ++m) {
    const unsigned short* Ct = C2 + (size_t)((t_base >> 4) + m) * TILE_E;

    short8 af[H_];
#pragma unroll
    for (int h = 0; h < H_; ++h)
      af[h] = *(const short8*)(Ct + (h * 4 + lo) * 128 + lr * 8);

    float wv[4][H_];
    const unsigned short* wp = Ct + 20 * 128 + lo * 32;
#pragma unroll
    for (int r = 0; r < 4; ++r) {
      short4v w4 = *(const short4v*)(wp + r * 8);
#pragma unroll
      for (int h = 0; h < H_; ++h) wv[r][h] = bf2f((unsigned short)w4[h]);
    }

    f32x4 o4[4];
#pragma unroll
    for (int n = 0; n < 4; ++n) {
      f32x4 o = zero;
#pragma unroll
      for (int h = 0; h < H_; ++h) {
        f32x4 c = __builtin_amdgcn_mfma_f32_16x16x32_bf16(af[h], bf[n], zero, 0, 0, 0);
#pragma unroll
        for (int r = 0; r < 4; ++r) o[r] += wv[r][h] * fmaxf(c[r], 0.f);
      }
      o4[n] = o;
    }

    // transpose via wave-private LDS: write C/D-layout, read row-contiguous
#pragma unroll
    for (int n = 0; n < 4; ++n)
#pragma unroll
      for (int r = 0; r < 4; ++r)
        tbuf[wid][lo * 4 + r][n * 16 + lr] = o4[n][r];

    float* Om = O + (size_t)(t_base + m * 16) * T_ + s_base;
#pragma unroll
    for (int j = 0; j < 4; ++j) {
      float4v v = *(const float4v*)&tbuf[wid][rr + 4 * j][cq];
      *(float4v*)(Om + (size_t)(rr + 4 * j) * T_ + cq) = v;
    }
  }
}

// ---------------------------------------------------------------------------
extern "C" void kernel_launch(void* const* d_in, const int* in_sizes, int n_in,
                              void* d_out, int out_size, void* d_ws, size_t ws_size,
                              hipStream_t stream) {
  const float* hs = (const float*)d_in[0];
  const float* Wq = (const float*)d_in[1];
  const float* Ww = (const float*)d_in[2];
  const float* Wk = (const float*)d_in[3];
  float* out = (float*)d_out;

  unsigned short* Wcb = (unsigned short*)d_ws;                      // 720,896 B
  unsigned short* Cb  = (unsigned short*)((char*)d_ws + (1 << 20)); // 2,883,584 B

  pack_weights<<<(NC * D_ + 255) / 256, 256, 0, stream>>>(Wq, Ww, Wk, Wcb);
  proj_kernel<<<ROWS / 16, 256, 0, stream>>>(hs, Wcb, Cb);
  dim3 g(T_ / 128, T_ / 128, B_);
  score_kernel<<<g, 256, 0, stream>>>(Cb, out);
}